// Round 2
// baseline (2038.379 us; speedup 1.0000x reference)
//
#include <hip/hip_runtime.h>

#define C_DIM 128
#define EPS_LN 1e-5f

// ---------------- zero-fill (replaces hipMemsetAsync) ----------------------
__global__ __launch_bounds__(256) void zero_kernel(float4* __restrict__ p, long n4) {
    long i = (long)blockIdx.x * blockDim.x + threadIdx.x;
    long stride = (long)gridDim.x * blockDim.x;
    float4 z = make_float4(0.f, 0.f, 0.f, 0.f);
    for (; i < n4; i += stride) p[i] = z;
}

// ---------------- LayerNorm: one wave (64 lanes) per row, 4 rows/block ------
__global__ __launch_bounds__(256) void ln_kernel(
    const float* __restrict__ x, const float* __restrict__ g,
    const float* __restrict__ b, float* __restrict__ out, int n) {
    int wave = threadIdx.x >> 6;
    int lane = threadIdx.x & 63;
    int row = blockIdx.x * 4 + wave;
    if (row >= n) return;
    float2 v = ((const float2*)(x + (size_t)row * C_DIM))[lane];
    float s  = v.x + v.y;
    float ss = v.x * v.x + v.y * v.y;
    #pragma unroll
    for (int o = 1; o < 64; o <<= 1) {
        s  += __shfl_xor(s, o);
        ss += __shfl_xor(ss, o);
    }
    float mu  = s * (1.0f / C_DIM);
    float var = ss * (1.0f / C_DIM) - mu * mu;
    float rs  = rsqrtf(var + EPS_LN);
    float2 gg = ((const float2*)g)[lane];
    float2 bb = ((const float2*)b)[lane];
    float2 o2;
    o2.x = (v.x - mu) * rs * gg.x + bb.x;
    o2.y = (v.y - mu) * rs * gg.y + bb.y;
    ((float2*)(out + (size_t)row * C_DIM))[lane] = o2;
}

// ---------------- Generic fp32 GEMM: C[M,128] = A[M,128] @ B[128,128](ldb) --
// tile 64 rows x 128 cols, 256 threads, 4x8 outputs/thread, BK=64
__global__ __launch_bounds__(256) void gemm128_kernel(
    const float* __restrict__ A, const float* __restrict__ B,
    const float* __restrict__ bias, float* __restrict__ Cd,
    const float* __restrict__ resid, int M, int ldb, int ldc,
    int relu, int accum) {
    __shared__ float As[64][65];
    __shared__ float Bs[64][132];   // 132: float4-aligned rows (528 B)
    int tid = threadIdx.x;
    int tx = tid & 15;   // col group: cols tx*8 .. tx*8+7
    int ty = tid >> 4;   // row group: rows ty*4 .. ty*4+3
    int row0 = blockIdx.x * 64;
    float acc[4][8];
    #pragma unroll
    for (int i = 0; i < 4; i++)
        #pragma unroll
        for (int j = 0; j < 8; j++) acc[i][j] = 0.f;

    for (int k0 = 0; k0 < 128; k0 += 64) {
        #pragma unroll
        for (int i = 0; i < 4; i++) {
            int idx = tid + i * 256;
            int r   = idx >> 4;
            int c4  = (idx & 15) * 4;
            int gr  = row0 + r;
            float4 val = make_float4(0.f, 0.f, 0.f, 0.f);
            if (gr < M) val = *(const float4*)(A + (size_t)gr * 128 + k0 + c4);
            As[r][c4 + 0] = val.x;
            As[r][c4 + 1] = val.y;
            As[r][c4 + 2] = val.z;
            As[r][c4 + 3] = val.w;
        }
        #pragma unroll
        for (int i = 0; i < 8; i++) {
            int idx = tid + i * 256;
            int r   = idx >> 5;
            int c4  = (idx & 31) * 4;
            *(float4*)&Bs[r][c4] = *(const float4*)(B + (size_t)(k0 + r) * ldb + c4);
        }
        __syncthreads();
        #pragma unroll
        for (int kk = 0; kk < 64; kk++) {
            float a[4];
            #pragma unroll
            for (int i = 0; i < 4; i++) a[i] = As[ty * 4 + i][kk];
            float b0[8];
            *(float4*)&b0[0] = *(float4*)&Bs[kk][tx * 8];
            *(float4*)&b0[4] = *(float4*)&Bs[kk][tx * 8 + 4];
            #pragma unroll
            for (int i = 0; i < 4; i++)
                #pragma unroll
                for (int j = 0; j < 8; j++)
                    acc[i][j] += a[i] * b0[j];
        }
        __syncthreads();
    }
    #pragma unroll
    for (int i = 0; i < 4; i++) {
        int gr = row0 + ty * 4 + i;
        if (gr >= M) continue;
        #pragma unroll
        for (int j = 0; j < 8; j++) {
            int col = tx * 8 + j;
            float v = acc[i][j];
            if (bias)  v += bias[col];
            if (resid) v += resid[(size_t)gr * 128 + col];
            if (relu)  v = fmaxf(v, 0.f);
            float* cp = Cd + (size_t)gr * ldc + col;
            if (accum) *cp += v; else *cp = v;
        }
    }
}

// ---------------- Edge pass 1: attention weights ---------------------------
// attn[e,h] = softmax_h( dot(Q[dst]_h, K[src]_h) / 4 )
__global__ __launch_bounds__(256) void attn_kernel(
    const float* __restrict__ Q, const float* __restrict__ K,
    const int* __restrict__ eidx, float* __restrict__ attn, int E_) {
    int wave = threadIdx.x >> 6;
    int lane = threadIdx.x & 63;
    int e = blockIdx.x * 4 + wave;
    if (e >= E_) return;
    int src = eidx[e];          // x_j
    int dst = eidx[E_ + e];     // x_i
    float2 q = ((const float2*)(Q + (size_t)dst * 128))[lane];
    float2 k = ((const float2*)(K + (size_t)src * 128))[lane];
    // per-head dot: head = lane>>3 (8 lanes x float2 = 16 elems)
    float p = q.x * k.x + q.y * k.y;
    p += __shfl_xor(p, 1);
    p += __shfl_xor(p, 2);
    p += __shfl_xor(p, 4);
    float s = p * 0.25f;   // / sqrt(HD=16)
    // softmax over 8 heads: xor-tree over group bits {8,16,32}
    float m = s;
    m = fmaxf(m, __shfl_xor(m, 8));
    m = fmaxf(m, __shfl_xor(m, 16));
    m = fmaxf(m, __shfl_xor(m, 32));
    float ex = expf(s - m);
    float sum = ex;
    sum += __shfl_xor(sum, 8);
    sum += __shfl_xor(sum, 16);
    sum += __shfl_xor(sum, 32);
    float a = ex / sum;
    if ((lane & 7) == 0) attn[(size_t)e * 8 + (lane >> 3)] = a;
}

// ---------------- Edge pass 2: weighted scatter-add ------------------------
__global__ __launch_bounds__(256) void aggr_kernel(
    const float* __restrict__ V, const float* __restrict__ attn,
    const int* __restrict__ eidx, float* __restrict__ ag, int E_) {
    int wave = threadIdx.x >> 6;
    int lane = threadIdx.x & 63;
    int e = blockIdx.x * 4 + wave;
    if (e >= E_) return;
    int src = eidx[e];
    int dst = eidx[E_ + e];
    float2 v = ((const float2*)(V + (size_t)src * 128))[lane];
    float a = attn[(size_t)e * 8 + (lane >> 3)];
    float* ap = ag + (size_t)dst * 128 + 2 * lane;
    atomicAdd(ap + 0, v.x * a);
    atomicAdd(ap + 1, v.y * a);
}

extern "C" void kernel_launch(void* const* d_in, const int* in_sizes, int n_in,
                              void* d_out, int out_size, void* d_ws, size_t ws_size,
                              hipStream_t stream) {
    const float* x   = (const float*)d_in[0];
    const int*  eidx = (const int*)d_in[1];
    const float* Wq = (const float*)d_in[2];  const float* bq = (const float*)d_in[3];
    const float* Wk = (const float*)d_in[4];  const float* bk = (const float*)d_in[5];
    const float* Wv = (const float*)d_in[6];  const float* bv = (const float*)d_in[7];
    const float* Wo = (const float*)d_in[8];  const float* bo = (const float*)d_in[9];
    const float* W1 = (const float*)d_in[10]; const float* b1 = (const float*)d_in[11];
    const float* W2 = (const float*)d_in[12]; const float* b2 = (const float*)d_in[13];
    const float* g1 = (const float*)d_in[14]; const float* be1 = (const float*)d_in[15];
    const float* g2 = (const float*)d_in[16]; const float* be2 = (const float*)d_in[17];
    float* out = (float*)d_out;

    int n  = in_sizes[0] / C_DIM;   // 100000
    int E_ = in_sizes[1] / 2;       // 600000

    // Workspace layout (peak 3*128*N + 8*E floats ~= 173 MB):
    //   bufA [N,128]: h1 -> ag -> h2
    //   bufB [N,128]: Q  -> u (FFN chunk)
    //   bufC [N,128]: K  -> V
    //   bufD [E,8]  : attn
    //   x2 lives in d_out (epilogue reads resid before writing same addr)
    float* ws = (float*)d_ws;
    float* bufA = ws;
    float* bufB = bufA + (size_t)n * 128;
    float* bufC = bufB + (size_t)n * 128;
    float* bufD = bufC + (size_t)n * 128;

    dim3 b256(256);
    dim3 lnGrid((n + 3) / 4);
    dim3 gGrid((n + 63) / 64);
    dim3 eGrid((E_ + 3) / 4);
    long n4 = (long)n * 128 / 4;
    dim3 zGrid((unsigned)((n4 + 255) / 256));

    // LN1: x -> h1(bufA)
    ln_kernel<<<lnGrid, b256, 0, stream>>>(x, g1, be1, bufA, n);
    // Q,K projections
    gemm128_kernel<<<gGrid, b256, 0, stream>>>(bufA, Wq, bq, bufB, nullptr, n, 128, 128, 0, 0);
    gemm128_kernel<<<gGrid, b256, 0, stream>>>(bufA, Wk, bk, bufC, nullptr, n, 128, 128, 0, 0);
    // attn weights (Q=bufB, K=bufC -> attn=bufD)
    attn_kernel<<<eGrid, b256, 0, stream>>>(bufB, bufC, eidx, bufD, E_);
    // V projection overwrites K (K dead after attn pass); reads h1(bufA)
    gemm128_kernel<<<gGrid, b256, 0, stream>>>(bufA, Wv, bv, bufC, nullptr, n, 128, 128, 0, 0);
    // zero aggregation buffer (reuses bufA; h1 dead after V proj)
    zero_kernel<<<zGrid, b256, 0, stream>>>((float4*)bufA, n4);
    // weighted scatter-add: ag(bufA) += attn * V
    aggr_kernel<<<eGrid, b256, 0, stream>>>(bufC, bufD, eidx, bufA, E_);
    // out projection + residual: x2 = ag@Wo + bo + x  -> stored in d_out
    gemm128_kernel<<<gGrid, b256, 0, stream>>>(bufA, Wo, bo, out, x, n, 128, 128, 0, 0);
    // LN2: d_out -> h2(bufC) (V dead after aggr)
    ln_kernel<<<lnGrid, b256, 0, stream>>>(out, g2, be2, bufC, n);
    // FFN in 4 column-chunks of W1 / row-chunks of W2; accumulate into out.
    // chunk0 adds b2 + resid(x2 in d_out, read-before-write per thread)
    for (int c = 0; c < 4; c++) {
        gemm128_kernel<<<gGrid, b256, 0, stream>>>(
            bufC, W1 + c * 128, b1 + c * 128, bufB, nullptr, n, 512, 128, 1, 0);
        gemm128_kernel<<<gGrid, b256, 0, stream>>>(
            bufB, W2 + (size_t)c * 128 * 128, (c == 0) ? b2 : nullptr, out,
            (c == 0) ? out : nullptr, n, 128, 128, 0, (c == 0) ? 0 : 1);
    }
}

// Round 3
// 976.688 us; speedup vs baseline: 2.0870x; 2.0870x over previous
//
#include <hip/hip_runtime.h>
#include <hip/hip_bf16.h>

#define C_DIM 128
#define EPS_LN 1e-5f

typedef short bf16x8 __attribute__((ext_vector_type(8)));
typedef float f32x4  __attribute__((ext_vector_type(4)));
typedef __hip_bfloat16 bf16;

// ---------------- weight convert + transpose: Wt[n][k] = bf16(W[k][n]) -----
__global__ __launch_bounds__(256) void wconv_kernel(
    const float* __restrict__ W, bf16* __restrict__ Wt, int K, int Nn) {
    int idx = blockIdx.x * 256 + threadIdx.x;
    if (idx >= K * Nn) return;
    int k = idx / Nn;
    int nn = idx - k * Nn;
    Wt[(size_t)nn * K + k] = __float2bfloat16(W[idx]);
}

// ---------------- zero ints ------------------------------------------------
__global__ __launch_bounds__(256) void zeroi_kernel(int* __restrict__ p, int n) {
    int i = blockIdx.x * 256 + threadIdx.x;
    if (i < n) p[i] = 0;
}

// ---------------- LayerNorm fp32 -> bf16, one wave per row -----------------
__global__ __launch_bounds__(256) void ln_kernel(
    const float* __restrict__ x, const float* __restrict__ g,
    const float* __restrict__ b, bf16* __restrict__ out, int n) {
    int wave = threadIdx.x >> 6;
    int lane = threadIdx.x & 63;
    int row = blockIdx.x * 4 + wave;
    if (row >= n) return;
    float2 v = ((const float2*)(x + (size_t)row * C_DIM))[lane];
    float s  = v.x + v.y;
    float ss = v.x * v.x + v.y * v.y;
    #pragma unroll
    for (int o = 1; o < 64; o <<= 1) {
        s  += __shfl_xor(s, o);
        ss += __shfl_xor(ss, o);
    }
    float mu  = s * (1.0f / C_DIM);
    float var = ss * (1.0f / C_DIM) - mu * mu;
    float rs  = rsqrtf(var + EPS_LN);
    float2 gg = ((const float2*)g)[lane];
    float2 bb = ((const float2*)b)[lane];
    __hip_bfloat162 o2;
    o2.x = __float2bfloat16((v.x - mu) * rs * gg.x + bb.x);
    o2.y = __float2bfloat16((v.y - mu) * rs * gg.y + bb.y);
    ((__hip_bfloat162*)(out + (size_t)row * C_DIM))[lane] = o2;
}

// ---------------- bf16 MFMA GEMM: C[M, 0:128] = A[M,Klen] @ Bt^T -----------
// A row-major [M, lda] bf16; Bt row-major [128, ldbt] bf16 (Bt[n][k]).
// 256 thr = 4 waves; wave handles 16 rows x 128 cols; no LDS (B is L1/L2-hot).
__global__ __launch_bounds__(256) void gemm_mfma_kernel(
    const bf16* __restrict__ A, int lda,
    const bf16* __restrict__ Bt, int ldbt,
    const float* __restrict__ bias,
    void* __restrict__ Cd, int ldc, int outBf16,
    const float* __restrict__ resid,
    int M, int Klen, int relu, int accum) {
    int lane = threadIdx.x & 63;
    int wv   = threadIdx.x >> 6;
    int m    = lane & 15;    // row-in-tile (A), col-in-tile (B, C)
    int q    = lane >> 4;    // quad
    int row0 = blockIdx.x * 64 + wv * 16;
    int aRow = row0 + m;
    bool aValid = aRow < M;
    const bf16* aPtr = A + (size_t)aRow * lda + q * 8;

    f32x4 acc[8];
    #pragma unroll
    for (int t = 0; t < 8; t++) acc[t] = (f32x4){0.f, 0.f, 0.f, 0.f};

    for (int k0 = 0; k0 < Klen; k0 += 32) {
        bf16x8 af;
        if (aValid) af = *(const bf16x8*)(aPtr + k0);
        else        af = (bf16x8){0, 0, 0, 0, 0, 0, 0, 0};
        #pragma unroll
        for (int t = 0; t < 8; t++) {
            bf16x8 bf = *(const bf16x8*)(Bt + (size_t)(t * 16 + m) * ldbt + k0 + q * 8);
            acc[t] = __builtin_amdgcn_mfma_f32_16x16x32_bf16(af, bf, acc[t], 0, 0, 0);
        }
    }
    // epilogue: C/D layout col=lane&15, row=q*4+reg
    #pragma unroll
    for (int t = 0; t < 8; t++) {
        int col = t * 16 + m;
        float bv = bias ? bias[col] : 0.f;
        #pragma unroll
        for (int r = 0; r < 4; r++) {
            int row = row0 + q * 4 + r;
            if (row >= M) continue;
            float v = acc[t][r] + bv;
            if (resid) v += resid[(size_t)row * ldc + col];
            if (relu)  v = fmaxf(v, 0.f);
            if (outBf16) {
                ((bf16*)Cd)[(size_t)row * ldc + col] = __float2bfloat16(v);
            } else {
                float* cp = (float*)Cd + (size_t)row * ldc + col;
                if (accum) *cp += v; else *cp = v;
            }
        }
    }
}

// ---------------- Edge pass 1: attention weights (bf16 Q,K) ----------------
__global__ __launch_bounds__(256) void attn_kernel(
    const bf16* __restrict__ Q, const bf16* __restrict__ K,
    const int* __restrict__ eidx, float* __restrict__ attn, int E_) {
    int wave = threadIdx.x >> 6;
    int lane = threadIdx.x & 63;
    int e = blockIdx.x * 4 + wave;
    if (e >= E_) return;
    int src = eidx[e];
    int dst = eidx[E_ + e];
    unsigned int uq = ((const unsigned int*)(Q + (size_t)dst * 128))[lane];
    unsigned int uk = ((const unsigned int*)(K + (size_t)src * 128))[lane];
    float qx = __uint_as_float((uq & 0xffffu) << 16);
    float qy = __uint_as_float(uq & 0xffff0000u);
    float kx = __uint_as_float((uk & 0xffffu) << 16);
    float ky = __uint_as_float(uk & 0xffff0000u);
    float p = qx * kx + qy * ky;
    p += __shfl_xor(p, 1);
    p += __shfl_xor(p, 2);
    p += __shfl_xor(p, 4);
    float s = p * 0.25f;   // / sqrt(16)
    float mx = s;
    mx = fmaxf(mx, __shfl_xor(mx, 8));
    mx = fmaxf(mx, __shfl_xor(mx, 16));
    mx = fmaxf(mx, __shfl_xor(mx, 32));
    float ex = expf(s - mx);
    float sum = ex;
    sum += __shfl_xor(sum, 8);
    sum += __shfl_xor(sum, 16);
    sum += __shfl_xor(sum, 32);
    float a = ex / sum;
    if ((lane & 7) == 0) attn[(size_t)e * 8 + (lane >> 3)] = a;
}

// ---------------- CSR build ------------------------------------------------
__global__ __launch_bounds__(256) void hist_kernel(
    const int* __restrict__ eidx, int* __restrict__ deg, int E_) {
    int e = blockIdx.x * 256 + threadIdx.x;
    if (e >= E_) return;
    atomicAdd(&deg[eidx[E_ + e]], 1);
}

__global__ __launch_bounds__(256) void alloc_kernel(
    const int* __restrict__ deg, int* __restrict__ start,
    int* __restrict__ cursor, int* __restrict__ counter, int n) {
    int i = blockIdx.x * 256 + threadIdx.x;
    if (i >= n) return;
    int d = deg[i];
    int s = atomicAdd(counter, d);
    start[i] = s;
    cursor[i] = s;
}

__global__ __launch_bounds__(256) void scatter_kernel(
    const int* __restrict__ eidx, int* __restrict__ cursor,
    int2* __restrict__ edata, int E_) {
    int e = blockIdx.x * 256 + threadIdx.x;
    if (e >= E_) return;
    int src = eidx[e];
    int dst = eidx[E_ + e];
    int pos = atomicAdd(&cursor[dst], 1);
    edata[pos] = make_int2(src, e);
}

// ---------------- Aggregation: one wave per node, no atomics ---------------
__global__ __launch_bounds__(256) void aggr_kernel(
    const bf16* __restrict__ V, const float* __restrict__ attn,
    const int* __restrict__ start, const int* __restrict__ deg,
    const int2* __restrict__ edata, bf16* __restrict__ ag, int n) {
    int wave = threadIdx.x >> 6;
    int lane = threadIdx.x & 63;
    int i = blockIdx.x * 4 + wave;
    if (i >= n) return;
    int s = start[i];
    int d = deg[i];
    float ax = 0.f, ay = 0.f;
    int h = lane >> 3;
    for (int j = s; j < s + d; j++) {
        int2 ed = edata[j];
        float a = attn[(size_t)ed.y * 8 + h];
        unsigned int uv = ((const unsigned int*)(V + (size_t)ed.x * 128))[lane];
        float vx = __uint_as_float((uv & 0xffffu) << 16);
        float vy = __uint_as_float(uv & 0xffff0000u);
        ax += a * vx;
        ay += a * vy;
    }
    __hip_bfloat162 o2;
    o2.x = __float2bfloat16(ax);
    o2.y = __float2bfloat16(ay);
    ((__hip_bfloat162*)(ag + (size_t)i * 128))[lane] = o2;
}

extern "C" void kernel_launch(void* const* d_in, const int* in_sizes, int n_in,
                              void* d_out, int out_size, void* d_ws, size_t ws_size,
                              hipStream_t stream) {
    const float* x   = (const float*)d_in[0];
    const int*  eidx = (const int*)d_in[1];
    const float* Wq = (const float*)d_in[2];  const float* bq = (const float*)d_in[3];
    const float* Wk = (const float*)d_in[4];  const float* bk = (const float*)d_in[5];
    const float* Wv = (const float*)d_in[6];  const float* bv = (const float*)d_in[7];
    const float* Wo = (const float*)d_in[8];  const float* bo = (const float*)d_in[9];
    const float* W1 = (const float*)d_in[10]; const float* b1 = (const float*)d_in[11];
    const float* W2 = (const float*)d_in[12]; const float* b2 = (const float*)d_in[13];
    const float* g1 = (const float*)d_in[14]; const float* be1 = (const float*)d_in[15];
    const float* g2 = (const float*)d_in[16]; const float* be2 = (const float*)d_in[17];
    float* out = (float*)d_out;

    int n  = in_sizes[0] / C_DIM;   // 100000
    int E_ = in_sizes[1] / 2;       // 600000
    size_t nf = (size_t)n * 128;

    // ---- workspace layout (~103 MB) ----
    bf16* wsb = (bf16*)d_ws;
    bf16* Wqt = wsb;                    // [128][128]
    bf16* Wkt = Wqt + 16384;
    bf16* Wvt = Wkt + 16384;
    bf16* Wot = Wvt + 16384;
    bf16* Wt1 = Wot + 16384;            // [512][128]
    bf16* Wt2 = Wt1 + 65536;            // [128][512]
    bf16* bufA = Wt2 + 65536;           // [N,128]: h1 -> ag ; FFN u cols 0.. (u spans bufA+bufC)
    bf16* bufC = bufA + nf;             // [N,128]: K -> V  ; u upper half
    bf16* bufB = bufC + nf;             // [N,128]: Q -> h2
    float* attnW = (float*)(bufB + nf); // [E,8] fp32
    int2* edata  = (int2*)(attnW + (size_t)E_ * 8);
    int* deg     = (int*)(edata + E_);
    int* start   = deg + n;
    int* cursor  = start + n;
    int* counter = cursor + n;          // 1 int

    dim3 b256(256);
    dim3 lnGrid((n + 3) / 4);
    dim3 gGrid((n + 63) / 64);
    dim3 eGrid4((E_ + 3) / 4);
    dim3 eGrid((E_ + 255) / 256);
    dim3 nGrid((n + 255) / 256);
    dim3 n4Grid((n + 3) / 4);

    // weights -> bf16 transposed
    wconv_kernel<<<dim3((16384 + 255) / 256), b256, 0, stream>>>(Wq, Wqt, 128, 128);
    wconv_kernel<<<dim3((16384 + 255) / 256), b256, 0, stream>>>(Wk, Wkt, 128, 128);
    wconv_kernel<<<dim3((16384 + 255) / 256), b256, 0, stream>>>(Wv, Wvt, 128, 128);
    wconv_kernel<<<dim3((16384 + 255) / 256), b256, 0, stream>>>(Wo, Wot, 128, 128);
    wconv_kernel<<<dim3((65536 + 255) / 256), b256, 0, stream>>>(W1, Wt1, 128, 512);
    wconv_kernel<<<dim3((65536 + 255) / 256), b256, 0, stream>>>(W2, Wt2, 512, 128);

    // LN1: x -> h1(bufA)
    ln_kernel<<<lnGrid, b256, 0, stream>>>(x, g1, be1, bufA, n);
    // Q(bufB), K(bufC)
    gemm_mfma_kernel<<<gGrid, b256, 0, stream>>>(bufA, 128, Wqt, 128, bq, bufB, 128, 1, nullptr, n, 128, 0, 0);
    gemm_mfma_kernel<<<gGrid, b256, 0, stream>>>(bufA, 128, Wkt, 128, bk, bufC, 128, 1, nullptr, n, 128, 0, 0);
    // attention weights
    attn_kernel<<<eGrid4, b256, 0, stream>>>(bufB, bufC, eidx, attnW, E_);
    // V overwrites K (bufC)
    gemm_mfma_kernel<<<gGrid, b256, 0, stream>>>(bufA, 128, Wvt, 128, bv, bufC, 128, 1, nullptr, n, 128, 0, 0);
    // CSR build (deg + counter zeroed; start order irrelevant)
    zeroi_kernel<<<nGrid, b256, 0, stream>>>(deg, n);
    zeroi_kernel<<<dim3(1), b256, 0, stream>>>(counter, 1);
    hist_kernel<<<eGrid, b256, 0, stream>>>(eidx, deg, E_);
    alloc_kernel<<<nGrid, b256, 0, stream>>>(deg, start, cursor, counter, n);
    scatter_kernel<<<eGrid, b256, 0, stream>>>(eidx, cursor, edata, E_);
    // aggregate: ag(bufA) (h1 dead after V proj)
    aggr_kernel<<<n4Grid, b256, 0, stream>>>(bufC, attnW, start, deg, edata, bufA, n);
    // x2 = ag@Wo + bo + x  -> d_out (fp32)
    gemm_mfma_kernel<<<gGrid, b256, 0, stream>>>(bufA, 128, Wot, 128, bo, out, 128, 0, x, n, 128, 0, 0);
    // LN2: out -> h2(bufB)
    ln_kernel<<<lnGrid, b256, 0, stream>>>(out, g2, be2, bufB, n);
    // FFN: 2 chunks of 256 hidden cols; u spans bufA+bufC ([N,256] bf16)
    bf16* uBuf = bufA;
    for (int c = 0; c < 2; c++) {
        for (int cc = 0; cc < 2; cc++) {
            int h0 = c * 256 + cc * 128;
            gemm_mfma_kernel<<<gGrid, b256, 0, stream>>>(
                bufB, 128, Wt1 + (size_t)h0 * 128, 128, b1 + h0,
                uBuf + cc * 128, 256, 1, nullptr, n, 128, 1, 0);
        }
        gemm_mfma_kernel<<<gGrid, b256, 0, stream>>>(
            uBuf, 256, Wt2 + c * 256, 512, (c == 0) ? b2 : nullptr,
            out, 128, 0, (c == 0) ? out : nullptr, n, 256, 0, (c == 1) ? 1 : 0);
    }
}

// Round 4
// 767.823 us; speedup vs baseline: 2.6548x; 1.2720x over previous
//
#include <hip/hip_runtime.h>
#include <hip/hip_bf16.h>

#define C_DIM 128
#define EPS_LN 1e-5f

typedef short bf16x8 __attribute__((ext_vector_type(8)));
typedef float f32x4  __attribute__((ext_vector_type(4)));
typedef __hip_bfloat16 bf16;

__device__ inline unsigned short f2bu(float f) {
    bf16 h = __float2bfloat16(f);
    return *reinterpret_cast<unsigned short*>(&h);
}
__device__ inline float blo(unsigned int u) { return __uint_as_float(u << 16); }
__device__ inline float bhi(unsigned int u) { return __uint_as_float(u & 0xffff0000u); }

__device__ inline ushort4 pack4(float a, float b, float c, float d) {
    ushort4 r; r.x = f2bu(a); r.y = f2bu(b); r.z = f2bu(c); r.w = f2bu(d); return r;
}

// ---------------- all-weights convert+transpose in ONE dispatch -------------
// dst layout (bf16): Wqt[128*128] Wkt Wvt Wot | Wt1[512][128] | Wt2[128][512]
__global__ __launch_bounds__(256) void wconv_all(
    const float* __restrict__ Wq, const float* __restrict__ Wk,
    const float* __restrict__ Wv, const float* __restrict__ Wo,
    const float* __restrict__ W1, const float* __restrict__ W2,
    bf16* __restrict__ dst) {
    int idx = blockIdx.x * 256 + threadIdx.x;
    if (idx < 65536) {                       // four 128x128 weights
        int r = idx >> 14, o = idx & 16383;
        int k = o >> 7, nn = o & 127;
        const float* W = (r == 0) ? Wq : (r == 1) ? Wk : (r == 2) ? Wv : Wo;
        dst[(r << 14) + nn * 128 + k] = __float2bfloat16(W[o]);
    } else if (idx < 131072) {               // W1 [128,512] -> Wt1[n][k]
        int o = idx - 65536;
        int k = o >> 9, nn = o & 511;
        dst[65536 + nn * 128 + k] = __float2bfloat16(W1[o]);
    } else if (idx < 196608) {               // W2 [512,128] -> Wt2[n][k]
        int o = idx - 131072;
        int k = o >> 7, nn = o & 127;
        dst[131072 + nn * 512 + k] = __float2bfloat16(W2[o]);
    }
}

__global__ __launch_bounds__(256) void zeroi_kernel(int* __restrict__ p, int n) {
    int i = blockIdx.x * 256 + threadIdx.x;
    if (i < n) p[i] = 0;
}

// ---------------- LayerNorm fp32 -> bf16, one wave per row -----------------
__global__ __launch_bounds__(256) void ln_kernel(
    const float* __restrict__ x, const float* __restrict__ g,
    const float* __restrict__ b, bf16* __restrict__ out, int n) {
    int wave = threadIdx.x >> 6;
    int lane = threadIdx.x & 63;
    int row = blockIdx.x * 4 + wave;
    if (row >= n) return;
    float2 v = ((const float2*)(x + (size_t)row * C_DIM))[lane];
    float s  = v.x + v.y;
    float ss = v.x * v.x + v.y * v.y;
    #pragma unroll
    for (int o = 1; o < 64; o <<= 1) {
        s  += __shfl_xor(s, o);
        ss += __shfl_xor(ss, o);
    }
    float mu  = s * (1.0f / C_DIM);
    float var = ss * (1.0f / C_DIM) - mu * mu;
    float rs  = rsqrtf(var + EPS_LN);
    float2 gg = ((const float2*)g)[lane];
    float2 bb = ((const float2*)b)[lane];
    __hip_bfloat162 o2;
    o2.x = __float2bfloat16((v.x - mu) * rs * gg.x + bb.x);
    o2.y = __float2bfloat16((v.y - mu) * rs * gg.y + bb.y);
    ((__hip_bfloat162*)(out + (size_t)row * C_DIM))[lane] = o2;
}

// ---------------- generic MFMA GEMM (operand-swapped C layout) -------------
// mfma(bfrag, afrag): lane(q,m) reg r holds C[row0+m][t*16+q*4+r] ->
// per-lane output = one row, 4 consecutive cols per t-tile (vector stores).
template<int NT, int KLEN, bool OUTBF16, bool RELU, bool ACCUM, bool FUSE_LN>
__global__ __launch_bounds__(256) void gemm_t(
    const bf16* __restrict__ A, int lda,
    const bf16* __restrict__ Bt, int ldbt,
    const float* __restrict__ bias,
    void* __restrict__ Cd, int ldc,
    const float* __restrict__ resid, int M,
    const float* __restrict__ g, const float* __restrict__ be,
    bf16* __restrict__ h2) {
    int lane = threadIdx.x & 63;
    int wv   = threadIdx.x >> 6;
    int m = lane & 15, q = lane >> 4;
    int row0 = blockIdx.x * 64 + wv * 16;
    int row  = row0 + m;
    bool valid = row < M;
    const bf16* aPtr = A + (size_t)row * lda + q * 8;

    f32x4 acc[NT];
    #pragma unroll
    for (int t = 0; t < NT; t++) acc[t] = (f32x4){0.f, 0.f, 0.f, 0.f};

    #pragma unroll
    for (int k0 = 0; k0 < KLEN; k0 += 32) {
        bf16x8 af;
        if (valid) af = *(const bf16x8*)(aPtr + k0);
        else       af = (bf16x8){0, 0, 0, 0, 0, 0, 0, 0};
        #pragma unroll
        for (int t = 0; t < NT; t++) {
            bf16x8 bf = *(const bf16x8*)(Bt + (size_t)(t * 16 + m) * ldbt + k0 + q * 8);
            acc[t] = __builtin_amdgcn_mfma_f32_16x16x32_bf16(bf, af, acc[t], 0, 0, 0);
        }
    }

    float vals[NT][4];
    #pragma unroll
    for (int t = 0; t < NT; t++) {
        int col = t * 16 + q * 4;
        float4 bv = make_float4(0.f, 0.f, 0.f, 0.f);
        if (bias) bv = *(const float4*)(bias + col);
        float4 rv = make_float4(0.f, 0.f, 0.f, 0.f);
        if (resid && valid) rv = *(const float4*)(resid + (size_t)row * ldc + col);
        vals[t][0] = acc[t][0] + bv.x + rv.x;
        vals[t][1] = acc[t][1] + bv.y + rv.y;
        vals[t][2] = acc[t][2] + bv.z + rv.z;
        vals[t][3] = acc[t][3] + bv.w + rv.w;
    }

    if (FUSE_LN) {
        // x2 = vals (fp32, -> Cd); h2 = LN(x2)*g+be (bf16). Row spans the 4
        // lanes {m, m+16, m+32, m+48} -> reduce via xor 16,32.
        float s1 = 0.f, s2 = 0.f;
        #pragma unroll
        for (int t = 0; t < NT; t++)
            #pragma unroll
            for (int r = 0; r < 4; r++) { s1 += vals[t][r]; s2 += vals[t][r] * vals[t][r]; }
        s1 += __shfl_xor(s1, 16); s1 += __shfl_xor(s1, 32);
        s2 += __shfl_xor(s2, 16); s2 += __shfl_xor(s2, 32);
        float mu  = s1 * (1.0f / 128.f);
        float var = s2 * (1.0f / 128.f) - mu * mu;
        float rs  = rsqrtf(var + EPS_LN);
        #pragma unroll
        for (int t = 0; t < NT; t++) {
            int col = t * 16 + q * 4;
            if (valid) {
                *(float4*)((float*)Cd + (size_t)row * ldc + col) =
                    make_float4(vals[t][0], vals[t][1], vals[t][2], vals[t][3]);
                float4 gg = *(const float4*)(g + col);
                float4 bb = *(const float4*)(be + col);
                ushort4 hv = pack4((vals[t][0] - mu) * rs * gg.x + bb.x,
                                   (vals[t][1] - mu) * rs * gg.y + bb.y,
                                   (vals[t][2] - mu) * rs * gg.z + bb.z,
                                   (vals[t][3] - mu) * rs * gg.w + bb.w);
                *(ushort4*)(h2 + (size_t)row * 128 + col) = hv;
            }
        }
        return;
    }

    #pragma unroll
    for (int t = 0; t < NT; t++) {
        int col = t * 16 + q * 4;
        if (!valid) continue;
        float v0 = vals[t][0], v1 = vals[t][1], v2 = vals[t][2], v3 = vals[t][3];
        if (RELU) {
            v0 = fmaxf(v0, 0.f); v1 = fmaxf(v1, 0.f);
            v2 = fmaxf(v2, 0.f); v3 = fmaxf(v3, 0.f);
        }
        if (OUTBF16) {
            *(ushort4*)((bf16*)Cd + (size_t)row * ldc + col) = pack4(v0, v1, v2, v3);
        } else {
            float* cp = (float*)Cd + (size_t)row * ldc + col;
            if (ACCUM) {
                float4 old = *(float4*)cp;
                *(float4*)cp = make_float4(old.x + v0, old.y + v1, old.z + v2, old.w + v3);
            } else {
                *(float4*)cp = make_float4(v0, v1, v2, v3);
            }
        }
    }
}

// ---------------- fused QKV: 3 GEMMs, A read once --------------------------
__global__ __launch_bounds__(256) void gemm_qkv(
    const bf16* __restrict__ A, const bf16* __restrict__ Wt,  // [384][128]
    const float* __restrict__ bq, const float* __restrict__ bk,
    const float* __restrict__ bv,
    bf16* __restrict__ Qo, bf16* __restrict__ Ko, bf16* __restrict__ Vo,
    int M) {
    int lane = threadIdx.x & 63;
    int wv   = threadIdx.x >> 6;
    int m = lane & 15, q = lane >> 4;
    int row0 = blockIdx.x * 64 + wv * 16;
    int row  = row0 + m;
    bool valid = row < M;
    const bf16* aPtr = A + (size_t)row * 128 + q * 8;

    f32x4 acc[24];
    #pragma unroll
    for (int t = 0; t < 24; t++) acc[t] = (f32x4){0.f, 0.f, 0.f, 0.f};

    #pragma unroll
    for (int k0 = 0; k0 < 128; k0 += 32) {
        bf16x8 af;
        if (valid) af = *(const bf16x8*)(aPtr + k0);
        else       af = (bf16x8){0, 0, 0, 0, 0, 0, 0, 0};
        #pragma unroll
        for (int t = 0; t < 24; t++) {
            bf16x8 bf = *(const bf16x8*)(Wt + (size_t)(t * 16 + m) * 128 + k0 + q * 8);
            acc[t] = __builtin_amdgcn_mfma_f32_16x16x32_bf16(bf, af, acc[t], 0, 0, 0);
        }
    }
    if (!valid) return;
    #pragma unroll
    for (int t = 0; t < 24; t++) {
        int grp = t >> 3;                 // 0:Q 1:K 2:V (compile-time per t)
        int col = (t & 7) * 16 + q * 4;
        const float* bp = (grp == 0) ? bq : (grp == 1) ? bk : bv;
        bf16*        op = (grp == 0) ? Qo : (grp == 1) ? Ko : Vo;
        float4 bvv = *(const float4*)(bp + col);
        *(ushort4*)(op + (size_t)row * 128 + col) =
            pack4(acc[t][0] + bvv.x, acc[t][1] + bvv.y,
                  acc[t][2] + bvv.z, acc[t][3] + bvv.w);
    }
}

// ---------------- attention: 8 edges/wave, one head per lane ---------------
__device__ inline float dot8(uint4 a, uint4 b) {
    return blo(a.x) * blo(b.x) + bhi(a.x) * bhi(b.x)
         + blo(a.y) * blo(b.y) + bhi(a.y) * bhi(b.y)
         + blo(a.z) * blo(b.z) + bhi(a.z) * bhi(b.z)
         + blo(a.w) * blo(b.w) + bhi(a.w) * bhi(b.w);
}

__global__ __launch_bounds__(256) void attn_kernel(
    const bf16* __restrict__ Q, const bf16* __restrict__ K,
    const int* __restrict__ eidx, float* __restrict__ attn, int E_) {
    int gw = blockIdx.x * 4 + (threadIdx.x >> 6);
    int lane = threadIdx.x & 63;
    int e = gw * 8 + (lane >> 3);
    int h = lane & 7;
    bool v = e < E_;
    int src = v ? eidx[e] : 0;
    int dst = v ? eidx[E_ + e] : 0;
    const uint4* qp = (const uint4*)(Q + (size_t)dst * 128 + h * 16);
    const uint4* kp = (const uint4*)(K + (size_t)src * 128 + h * 16);
    uint4 q0 = qp[0], q1 = qp[1];
    uint4 k0 = kp[0], k1 = kp[1];
    float s = (dot8(q0, k0) + dot8(q1, k1)) * 0.25f;   // / sqrt(16)
    float mx = s;
    mx = fmaxf(mx, __shfl_xor(mx, 1));
    mx = fmaxf(mx, __shfl_xor(mx, 2));
    mx = fmaxf(mx, __shfl_xor(mx, 4));
    float ex = expf(s - mx);
    float sum = ex;
    sum += __shfl_xor(sum, 1);
    sum += __shfl_xor(sum, 2);
    sum += __shfl_xor(sum, 4);
    if (v) attn[(size_t)e * 8 + h] = ex / sum;   // coalesced: gw*64+lane
}

// ---------------- CSR build ------------------------------------------------
__global__ __launch_bounds__(256) void hist_kernel(
    const int* __restrict__ eidx, int* __restrict__ deg, int E_) {
    int e = blockIdx.x * 256 + threadIdx.x;
    if (e >= E_) return;
    atomicAdd(&deg[eidx[E_ + e]], 1);
}

__global__ __launch_bounds__(256) void alloc_kernel(
    const int* __restrict__ deg, int* __restrict__ start,
    int* __restrict__ cursor, int* __restrict__ counter, int n) {
    int i = blockIdx.x * 256 + threadIdx.x;
    if (i >= n) return;
    int d = deg[i];
    int s = atomicAdd(counter, d);
    start[i] = s;
    cursor[i] = s;
}

__global__ __launch_bounds__(256) void scatter_kernel(
    const int* __restrict__ eidx, int* __restrict__ cursor,
    int2* __restrict__ edata, int E_) {
    int e = blockIdx.x * 256 + threadIdx.x;
    if (e >= E_) return;
    int src = eidx[e];
    int dst = eidx[E_ + e];
    int pos = atomicAdd(&cursor[dst], 1);
    edata[pos] = make_int2(src, e);
}

// ---------------- aggregation: one wave/node, 2-way unrolled ---------------
__global__ __launch_bounds__(256) void aggr_kernel(
    const bf16* __restrict__ V, const float* __restrict__ attnW,
    const int* __restrict__ start, const int* __restrict__ deg,
    const int2* __restrict__ edata, bf16* __restrict__ ag, int n) {
    int wave = threadIdx.x >> 6;
    int lane = threadIdx.x & 63;
    int i = blockIdx.x * 4 + wave;
    if (i >= n) return;
    int s = start[i], d = deg[i];
    int h = lane >> 3;
    float ax = 0.f, ay = 0.f, bx = 0.f, by = 0.f;
    int j = s, e_ = s + d;
    for (; j + 2 <= e_; j += 2) {
        int2 e0 = edata[j], e1 = edata[j + 1];
        float a0 = attnW[(size_t)e0.y * 8 + h];
        float a1 = attnW[(size_t)e1.y * 8 + h];
        unsigned u0 = ((const unsigned*)(V + (size_t)e0.x * 128))[lane];
        unsigned u1 = ((const unsigned*)(V + (size_t)e1.x * 128))[lane];
        ax += a0 * blo(u0); ay += a0 * bhi(u0);
        bx += a1 * blo(u1); by += a1 * bhi(u1);
    }
    if (j < e_) {
        int2 e0 = edata[j];
        float a0 = attnW[(size_t)e0.y * 8 + h];
        unsigned u0 = ((const unsigned*)(V + (size_t)e0.x * 128))[lane];
        ax += a0 * blo(u0); ay += a0 * bhi(u0);
    }
    ax += bx; ay += by;
    __hip_bfloat162 o2;
    o2.x = __float2bfloat16(ax);
    o2.y = __float2bfloat16(ay);
    ((__hip_bfloat162*)(ag + (size_t)i * 128))[lane] = o2;
}

extern "C" void kernel_launch(void* const* d_in, const int* in_sizes, int n_in,
                              void* d_out, int out_size, void* d_ws, size_t ws_size,
                              hipStream_t stream) {
    const float* x   = (const float*)d_in[0];
    const int*  eidx = (const int*)d_in[1];
    const float* Wq = (const float*)d_in[2];  const float* bq = (const float*)d_in[3];
    const float* Wk = (const float*)d_in[4];  const float* bk = (const float*)d_in[5];
    const float* Wv = (const float*)d_in[6];  const float* bv = (const float*)d_in[7];
    const float* Wo = (const float*)d_in[8];  const float* bo = (const float*)d_in[9];
    const float* W1 = (const float*)d_in[10]; const float* b1 = (const float*)d_in[11];
    const float* W2 = (const float*)d_in[12]; const float* b2 = (const float*)d_in[13];
    const float* g1 = (const float*)d_in[14]; const float* be1 = (const float*)d_in[15];
    const float* g2 = (const float*)d_in[16]; const float* be2 = (const float*)d_in[17];
    float* out = (float*)d_out;

    int n  = in_sizes[0] / C_DIM;   // 100000
    int E_ = in_sizes[1] / 2;       // 600000
    size_t nf = (size_t)n * 128;

    // ---- workspace (~128 MB) ----
    bf16* Wt   = (bf16*)d_ws;            // 196608 bf16: Wq|Wk|Wv|Wo|W1|W2 (transposed)
    bf16* Wt1  = Wt + 65536;
    bf16* Wt2  = Wt + 131072;
    bf16* bufA = Wt + 196608;            // h1 -> ag -> u[:,0:?] (u spans A+C)
    bf16* bufC = bufA + nf;              // K  -> u upper half
    bf16* bufB = bufC + nf;              // Q  -> h2
    bf16* bufV = bufB + nf;              // V
    float* attnW = (float*)(bufV + nf);  // [E,8] fp32
    int2* edata  = (int2*)(attnW + (size_t)E_ * 8);
    int*  ideg   = (int*)(edata + E_);   // deg[n] | counter[1] | start[n] | cursor[n]
    int*  counter = ideg + n;
    int*  istart  = ideg + n + 1;
    int*  icursor = istart + n;

    dim3 b256(256);
    dim3 lnGrid((n + 3) / 4);
    dim3 gGrid((n + 63) / 64);
    dim3 eGrid8((E_ + 31) / 32);         // 8 edges/wave, 4 waves/block
    dim3 eGrid((E_ + 255) / 256);
    dim3 nGrid((n + 255) / 256);
    dim3 n1Grid((n + 1 + 255) / 256);
    dim3 n4Grid((n + 3) / 4);

    // weights -> bf16 transposed (one dispatch)
    wconv_all<<<dim3(768), b256, 0, stream>>>(Wq, Wk, Wv, Wo, W1, W2, Wt);
    // zero deg+counter (contiguous n+1 ints)
    zeroi_kernel<<<n1Grid, b256, 0, stream>>>(ideg, n + 1);
    // LN1: x -> h1(bufA)
    ln_kernel<<<lnGrid, b256, 0, stream>>>(x, g1, be1, bufA, n);
    // fused QKV: h1 -> Q(bufB), K(bufC), V(bufV)
    gemm_qkv<<<gGrid, b256, 0, stream>>>(bufA, Wt, bq, bk, bv, bufB, bufC, bufV, n);
    // attention weights
    attn_kernel<<<eGrid8, b256, 0, stream>>>(bufB, bufC, eidx, attnW, E_);
    // CSR build
    hist_kernel<<<eGrid, b256, 0, stream>>>(eidx, ideg, E_);
    alloc_kernel<<<nGrid, b256, 0, stream>>>(ideg, istart, icursor, counter, n);
    scatter_kernel<<<eGrid, b256, 0, stream>>>(eidx, icursor, edata, E_);
    // aggregate into ag(bufA); h1 dead
    aggr_kernel<<<n4Grid, b256, 0, stream>>>(bufV, attnW, istart, ideg, edata, bufA, n);
    // Wo GEMM + residual + fused LN2: x2 -> d_out (fp32), h2 -> bufB (bf16)
    gemm_t<8, 128, false, false, false, true><<<gGrid, b256, 0, stream>>>(
        bufA, 128, Wt + 49152, 128, bo, out, 128, x, n, g2, be2, bufB);
    // FFN: two 256-wide hidden chunks; u spans bufA..bufC ([N,256] bf16)
    for (int c = 0; c < 2; c++) {
        gemm_t<16, 128, true, true, false, false><<<gGrid, b256, 0, stream>>>(
            bufB, 128, Wt1 + (size_t)c * 256 * 128, 128, b1 + c * 256,
            bufA, 256, nullptr, n, nullptr, nullptr, nullptr);
        if (c == 0) {
            gemm_t<8, 256, false, false, false, false><<<gGrid, b256, 0, stream>>>(
                bufA, 256, Wt2, 512, b2, out, 128, out, n, nullptr, nullptr, nullptr);
        } else {
            gemm_t<8, 256, false, false, true, false><<<gGrid, b256, 0, stream>>>(
                bufA, 256, Wt2 + 256, 512, nullptr, out, 128, nullptr, n,
                nullptr, nullptr, nullptr);
        }
    }
}

// Round 5
// 519.633 us; speedup vs baseline: 3.9227x; 1.4776x over previous
//
#include <hip/hip_runtime.h>
#include <hip/hip_bf16.h>

#define C_DIM 128
#define EPS_LN 1e-5f

typedef short bf16x8 __attribute__((ext_vector_type(8)));
typedef float f32x4  __attribute__((ext_vector_type(4)));
typedef __hip_bfloat16 bf16;

__device__ inline unsigned short f2bu(float f) {
    bf16 h = __float2bfloat16(f);
    return *reinterpret_cast<unsigned short*>(&h);
}
__device__ inline float blo(unsigned int u) { return __uint_as_float(u << 16); }
__device__ inline float bhi(unsigned int u) { return __uint_as_float(u & 0xffff0000u); }
__device__ inline ushort4 pack4(float a, float b, float c, float d) {
    ushort4 r; r.x = f2bu(a); r.y = f2bu(b); r.z = f2bu(c); r.w = f2bu(d); return r;
}

// ---------------- weights convert+transpose + bias pack, ONE dispatch ------
// dst (bf16): Wqt|Wkt|Wvt|Wot (4x 128*128) | Wt1[512][128] | Wt2[128][512]
// then packed fp32 bqkv[384] right after.
__global__ __launch_bounds__(256) void wconv_all(
    const float* __restrict__ Wq, const float* __restrict__ Wk,
    const float* __restrict__ Wv, const float* __restrict__ Wo,
    const float* __restrict__ W1, const float* __restrict__ W2,
    const float* __restrict__ bq, const float* __restrict__ bk,
    const float* __restrict__ bv, bf16* __restrict__ dst) {
    int idx = blockIdx.x * 256 + threadIdx.x;
    if (idx < 65536) {                       // four 128x128 weights
        int r = idx >> 14, o = idx & 16383;
        int k = o >> 7, nn = o & 127;
        const float* W = (r == 0) ? Wq : (r == 1) ? Wk : (r == 2) ? Wv : Wo;
        dst[(r << 14) + nn * 128 + k] = __float2bfloat16(W[o]);
    } else if (idx < 131072) {               // W1 [128,512] -> Wt1[n][k]
        int o = idx - 65536;
        int k = o >> 9, nn = o & 511;
        dst[65536 + nn * 128 + k] = __float2bfloat16(W1[o]);
    } else if (idx < 196608) {               // W2 [512,128] -> Wt2[n][k]
        int o = idx - 131072;
        int k = o >> 7, nn = o & 127;
        dst[131072 + nn * 512 + k] = __float2bfloat16(W2[o]);
    } else if (idx < 196992) {               // packed bqkv[384] fp32
        int j = idx - 196608;
        int grp = j >> 7, col = j & 127;
        const float* bp = (grp == 0) ? bq : (grp == 1) ? bk : bv;
        ((float*)(dst + 196608))[j] = bp[col];
    }
}

__global__ __launch_bounds__(256) void zeroi_kernel(int* __restrict__ p, int n) {
    int i = blockIdx.x * 256 + threadIdx.x;
    if (i < n) p[i] = 0;
}

// ---------------- LayerNorm fp32 -> bf16, one wave per row -----------------
__global__ __launch_bounds__(256) void ln_kernel(
    const float* __restrict__ x, const float* __restrict__ g,
    const float* __restrict__ b, bf16* __restrict__ out, int n) {
    int wave = threadIdx.x >> 6;
    int lane = threadIdx.x & 63;
    int row = blockIdx.x * 4 + wave;
    if (row >= n) return;
    float2 v = ((const float2*)(x + (size_t)row * C_DIM))[lane];
    float s  = v.x + v.y;
    float ss = v.x * v.x + v.y * v.y;
    #pragma unroll
    for (int o = 1; o < 64; o <<= 1) {
        s  += __shfl_xor(s, o);
        ss += __shfl_xor(ss, o);
    }
    float mu  = s * (1.0f / C_DIM);
    float var = ss * (1.0f / C_DIM) - mu * mu;
    float rs  = rsqrtf(var + EPS_LN);
    float2 gg = ((const float2*)g)[lane];
    float2 bb = ((const float2*)b)[lane];
    __hip_bfloat162 o2;
    o2.x = __float2bfloat16((v.x - mu) * rs * gg.x + bb.x);
    o2.y = __float2bfloat16((v.y - mu) * rs * gg.y + bb.y);
    ((__hip_bfloat162*)(out + (size_t)row * C_DIM))[lane] = o2;
}

// ---------------- LDS-staged MFMA GEMM -------------------------------------
// Block: 128 rows x 128 cols of C; 4 waves, each 32 rows x 128 cols.
// A [M,lda] bf16 row-major; Bt [Ncols][Kfull] bf16 (row = output col).
// Output col-block = blockIdx.y: Bt rows colBlk*128.., bias biasBase+colBlk*128,
// C pointer = Cd + colBlk*obStride (elements).
// Operand-swapped mfma(bf, af, acc): lane(m,q) reg r = C[row0+..+m][ct*16+q*4+r].
template<bool OUTBF16, bool RELU, bool FUSE_LN, int KSTEPS>
__global__ __launch_bounds__(256) void gemm_lds(
    const bf16* __restrict__ A, int lda,
    const bf16* __restrict__ Bt, int Kfull,
    const float* __restrict__ biasBase,
    void* __restrict__ Cd, int ldc, size_t obStride,
    const float* __restrict__ resid, int ldres,
    int M,
    const float* __restrict__ g, const float* __restrict__ be,
    bf16* __restrict__ h2) {
    __shared__ bf16 As[128][136];   // +8 pad: frag reads 2-way (free)
    __shared__ bf16 Bs[128][136];
    int tid  = threadIdx.x;
    int lane = tid & 63;
    int w    = tid >> 6;
    int m = lane & 15, q = lane >> 4;
    int row0 = blockIdx.x * 128;
    const bf16* Bbase = Bt + (size_t)blockIdx.y * 128 * Kfull;

    f32x4 acc[2][8];
    #pragma unroll
    for (int rt = 0; rt < 2; rt++)
        #pragma unroll
        for (int ct = 0; ct < 8; ct++) acc[rt][ct] = (f32x4){0.f, 0.f, 0.f, 0.f};

    int sr = tid >> 1, sch = tid & 1;        // staging: row, 128B-half
    int gr = row0 + sr;

    for (int kt = 0; kt < KSTEPS; kt++) {
        // stage A tile [128][128]
        {
            const uint4* gp = (const uint4*)(A + (size_t)gr * lda + kt * 128 + sch * 64);
            uint4* sp = (uint4*)&As[sr][sch * 64];
            if (gr < M) {
                #pragma unroll
                for (int i = 0; i < 8; i++) sp[i] = gp[i];
            } else {
                uint4 z = make_uint4(0, 0, 0, 0);
                #pragma unroll
                for (int i = 0; i < 8; i++) sp[i] = z;
            }
        }
        // stage B tile [128][128] (Ncols always multiple of 128)
        {
            const uint4* gp = (const uint4*)(Bbase + (size_t)sr * Kfull + kt * 128 + sch * 64);
            uint4* sp = (uint4*)&Bs[sr][sch * 64];
            #pragma unroll
            for (int i = 0; i < 8; i++) sp[i] = gp[i];
        }
        __syncthreads();
        #pragma unroll
        for (int ks = 0; ks < 4; ks++) {
            bf16x8 af0 = *(const bf16x8*)&As[w * 32 + m][ks * 32 + q * 8];
            bf16x8 af1 = *(const bf16x8*)&As[w * 32 + 16 + m][ks * 32 + q * 8];
            #pragma unroll
            for (int ct = 0; ct < 8; ct++) {
                bf16x8 bf = *(const bf16x8*)&Bs[ct * 16 + m][ks * 32 + q * 8];
                acc[0][ct] = __builtin_amdgcn_mfma_f32_16x16x32_bf16(bf, af0, acc[0][ct], 0, 0, 0);
                acc[1][ct] = __builtin_amdgcn_mfma_f32_16x16x32_bf16(bf, af1, acc[1][ct], 0, 0, 0);
            }
        }
        if (kt + 1 < KSTEPS) __syncthreads();
    }

    // ---- epilogue ----
    #pragma unroll
    for (int rt = 0; rt < 2; rt++) {
        int row = row0 + w * 32 + rt * 16 + m;
        bool valid = row < M;
        float vals[8][4];
        #pragma unroll
        for (int ct = 0; ct < 8; ct++) {
            int col = ct * 16 + q * 4;
            float4 bv = make_float4(0.f, 0.f, 0.f, 0.f);
            if (biasBase) bv = *(const float4*)(biasBase + blockIdx.y * 128 + col);
            float4 rv = make_float4(0.f, 0.f, 0.f, 0.f);
            if (resid && valid) rv = *(const float4*)(resid + (size_t)row * ldres + col);
            vals[ct][0] = acc[rt][ct][0] + bv.x + rv.x;
            vals[ct][1] = acc[rt][ct][1] + bv.y + rv.y;
            vals[ct][2] = acc[rt][ct][2] + bv.z + rv.z;
            vals[ct][3] = acc[rt][ct][3] + bv.w + rv.w;
        }
        if (FUSE_LN) {
            // row spans lanes {m, m+16, m+32, m+48}: reduce over q via xor 16,32
            float s1 = 0.f, s2 = 0.f;
            #pragma unroll
            for (int ct = 0; ct < 8; ct++)
                #pragma unroll
                for (int r = 0; r < 4; r++) { s1 += vals[ct][r]; s2 += vals[ct][r] * vals[ct][r]; }
            s1 += __shfl_xor(s1, 16); s1 += __shfl_xor(s1, 32);
            s2 += __shfl_xor(s2, 16); s2 += __shfl_xor(s2, 32);
            float mu  = s1 * (1.0f / 128.f);
            float var = s2 * (1.0f / 128.f) - mu * mu;
            float rs  = rsqrtf(var + EPS_LN);
            if (valid) {
                #pragma unroll
                for (int ct = 0; ct < 8; ct++) {
                    int col = ct * 16 + q * 4;
                    *(float4*)((float*)Cd + (size_t)row * ldc + col) =
                        make_float4(vals[ct][0], vals[ct][1], vals[ct][2], vals[ct][3]);
                    float4 gg = *(const float4*)(g + col);
                    float4 bb = *(const float4*)(be + col);
                    *(ushort4*)(h2 + (size_t)row * 128 + col) =
                        pack4((vals[ct][0] - mu) * rs * gg.x + bb.x,
                              (vals[ct][1] - mu) * rs * gg.y + bb.y,
                              (vals[ct][2] - mu) * rs * gg.z + bb.z,
                              (vals[ct][3] - mu) * rs * gg.w + bb.w);
                }
            }
        } else if (valid) {
            #pragma unroll
            for (int ct = 0; ct < 8; ct++) {
                int col = ct * 16 + q * 4;
                float v0 = vals[ct][0], v1 = vals[ct][1];
                float v2 = vals[ct][2], v3 = vals[ct][3];
                if (RELU) {
                    v0 = fmaxf(v0, 0.f); v1 = fmaxf(v1, 0.f);
                    v2 = fmaxf(v2, 0.f); v3 = fmaxf(v3, 0.f);
                }
                if (OUTBF16) {
                    *(ushort4*)((bf16*)Cd + blockIdx.y * obStride + (size_t)row * ldc + col) =
                        pack4(v0, v1, v2, v3);
                } else {
                    *(float4*)((float*)Cd + blockIdx.y * obStride + (size_t)row * ldc + col) =
                        make_float4(v0, v1, v2, v3);
                }
            }
        }
    }
}

// ---------------- attention: 8 edges/wave, one head per lane ---------------
__device__ inline float dot8(uint4 a, uint4 b) {
    return blo(a.x) * blo(b.x) + bhi(a.x) * bhi(b.x)
         + blo(a.y) * blo(b.y) + bhi(a.y) * bhi(b.y)
         + blo(a.z) * blo(b.z) + bhi(a.z) * bhi(b.z)
         + blo(a.w) * blo(b.w) + bhi(a.w) * bhi(b.w);
}

__global__ __launch_bounds__(256) void attn_kernel(
    const bf16* __restrict__ Q, const bf16* __restrict__ K,
    const int* __restrict__ eidx, float* __restrict__ attn, int E_) {
    int gw = blockIdx.x * 4 + (threadIdx.x >> 6);
    int lane = threadIdx.x & 63;
    int e = gw * 8 + (lane >> 3);
    int h = lane & 7;
    bool v = e < E_;
    int src = v ? eidx[e] : 0;
    int dst = v ? eidx[E_ + e] : 0;
    const uint4* qp = (const uint4*)(Q + (size_t)dst * 128 + h * 16);
    const uint4* kp = (const uint4*)(K + (size_t)src * 128 + h * 16);
    uint4 q0 = qp[0], q1 = qp[1];
    uint4 k0 = kp[0], k1 = kp[1];
    float s = (dot8(q0, k0) + dot8(q1, k1)) * 0.25f;   // / sqrt(16)
    float mx = s;
    mx = fmaxf(mx, __shfl_xor(mx, 1));
    mx = fmaxf(mx, __shfl_xor(mx, 2));
    mx = fmaxf(mx, __shfl_xor(mx, 4));
    float ex = expf(s - mx);
    float sum = ex;
    sum += __shfl_xor(sum, 1);
    sum += __shfl_xor(sum, 2);
    sum += __shfl_xor(sum, 4);
    if (v) attn[(size_t)e * 8 + h] = ex / sum;   // coalesced: gw*64+lane
}

// ---------------- CSR build ------------------------------------------------
__global__ __launch_bounds__(256) void hist_kernel(
    const int* __restrict__ eidx, int* __restrict__ deg, int E_) {
    int e = blockIdx.x * 256 + threadIdx.x;
    if (e >= E_) return;
    atomicAdd(&deg[eidx[E_ + e]], 1);
}

__global__ __launch_bounds__(256) void alloc_kernel(
    const int* __restrict__ deg, int* __restrict__ start,
    int* __restrict__ cursor, int* __restrict__ counter, int n) {
    int i = blockIdx.x * 256 + threadIdx.x;
    if (i >= n) return;
    int d = deg[i];
    int s = atomicAdd(counter, d);
    start[i] = s;
    cursor[i] = s;
}

__global__ __launch_bounds__(256) void scatter_kernel(
    const int* __restrict__ eidx, int* __restrict__ cursor,
    int2* __restrict__ edata, int E_) {
    int e = blockIdx.x * 256 + threadIdx.x;
    if (e >= E_) return;
    int src = eidx[e];
    int dst = eidx[E_ + e];
    int pos = atomicAdd(&cursor[dst], 1);
    edata[pos] = make_int2(src, e);
}

// ---------------- aggregation: one wave/node, 2-way unrolled ---------------
__global__ __launch_bounds__(256) void aggr_kernel(
    const bf16* __restrict__ V, const float* __restrict__ attnW,
    const int* __restrict__ start, const int* __restrict__ deg,
    const int2* __restrict__ edata, bf16* __restrict__ ag, int n) {
    int wave = threadIdx.x >> 6;
    int lane = threadIdx.x & 63;
    int i = blockIdx.x * 4 + wave;
    if (i >= n) return;
    int s = start[i], d = deg[i];
    int h = lane >> 3;
    float ax = 0.f, ay = 0.f, bx = 0.f, by = 0.f;
    int j = s, e_ = s + d;
    for (; j + 2 <= e_; j += 2) {
        int2 e0 = edata[j], e1 = edata[j + 1];
        float a0 = attnW[(size_t)e0.y * 8 + h];
        float a1 = attnW[(size_t)e1.y * 8 + h];
        unsigned u0 = ((const unsigned*)(V + (size_t)e0.x * 128))[lane];
        unsigned u1 = ((const unsigned*)(V + (size_t)e1.x * 128))[lane];
        ax += a0 * blo(u0); ay += a0 * bhi(u0);
        bx += a1 * blo(u1); by += a1 * bhi(u1);
    }
    if (j < e_) {
        int2 e0 = edata[j];
        float a0 = attnW[(size_t)e0.y * 8 + h];
        unsigned u0 = ((const unsigned*)(V + (size_t)e0.x * 128))[lane];
        ax += a0 * blo(u0); ay += a0 * bhi(u0);
    }
    ax += bx; ay += by;
    __hip_bfloat162 o2;
    o2.x = __float2bfloat16(ax);
    o2.y = __float2bfloat16(ay);
    ((__hip_bfloat162*)(ag + (size_t)i * 128))[lane] = o2;
}

extern "C" void kernel_launch(void* const* d_in, const int* in_sizes, int n_in,
                              void* d_out, int out_size, void* d_ws, size_t ws_size,
                              hipStream_t stream) {
    const float* x   = (const float*)d_in[0];
    const int*  eidx = (const int*)d_in[1];
    const float* Wq = (const float*)d_in[2];  const float* bq = (const float*)d_in[3];
    const float* Wk = (const float*)d_in[4];  const float* bk = (const float*)d_in[5];
    const float* Wv = (const float*)d_in[6];  const float* bv = (const float*)d_in[7];
    const float* Wo = (const float*)d_in[8];  const float* bo = (const float*)d_in[9];
    const float* W1 = (const float*)d_in[10]; const float* b1 = (const float*)d_in[11];
    const float* W2 = (const float*)d_in[12]; const float* b2 = (const float*)d_in[13];
    const float* g1 = (const float*)d_in[14]; const float* be1 = (const float*)d_in[15];
    const float* g2 = (const float*)d_in[16]; const float* be2 = (const float*)d_in[17];
    float* out = (float*)d_out;

    int n  = in_sizes[0] / C_DIM;   // 100000
    int E_ = in_sizes[1] / 2;       // 600000
    size_t nf = (size_t)n * 128;

    // ---- workspace (~154 MB) ----
    bf16* Wt    = (bf16*)d_ws;                // 196608 bf16 transposed weights
    float* bqkv = (float*)(Wt + 196608);      // packed [bq|bk|bv]
    bf16* reg0  = (bf16*)(bqkv + 384);        // 4*nf: h1|Q|K|V ; u overlays all
    bf16* h1 = reg0;
    bf16* Qb = reg0 + nf;
    bf16* Kb = reg0 + 2 * nf;
    bf16* Vb = reg0 + 3 * nf;
    bf16* uB = reg0;                          // [N,512] bf16 (FFN intermediate)
    bf16* ag = reg0 + 4 * nf;                 // [N,128]
    char* r2 = (char*)(ag + nf);              // union region
    float* attnW = (float*)r2;                // [E,8] fp32
    int2* edata  = (int2*)(attnW + (size_t)E_ * 8);
    int*  ideg   = (int*)(edata + E_);
    int*  counter = ideg + n;
    int*  istart  = ideg + n + 1;
    int*  icursor = istart + n;
    bf16* h2 = (bf16*)r2;                     // overlays attnW/edata/CSR after aggr

    dim3 b256(256);
    dim3 lnGrid((n + 3) / 4);
    int rb = (n + 127) / 128;                 // 782
    dim3 eGrid8((E_ + 31) / 32);
    dim3 eGrid((E_ + 255) / 256);
    dim3 nGrid((n + 255) / 256);
    dim3 n1Grid((n + 1 + 255) / 256);
    dim3 n4Grid((n + 3) / 4);

    // weights -> bf16 transposed + packed bqkv (one dispatch)
    wconv_all<<<dim3(770), b256, 0, stream>>>(Wq, Wk, Wv, Wo, W1, W2, bq, bk, bv, Wt);
    // zero deg+counter
    zeroi_kernel<<<n1Grid, b256, 0, stream>>>(ideg, n + 1);
    // LN1: x -> h1
    ln_kernel<<<lnGrid, b256, 0, stream>>>(x, g1, be1, h1, n);
    // QKV: one dispatch, col-blocks -> Q|K|V buffers (obStride = nf)
    gemm_lds<true, false, false, 1><<<dim3(rb, 3), b256, 0, stream>>>(
        h1, 128, Wt, 128, bqkv, Qb, 128, nf, nullptr, 0, n, nullptr, nullptr, nullptr);
    // attention weights
    attn_kernel<<<eGrid8, b256, 0, stream>>>(Qb, Kb, eidx, attnW, E_);
    // CSR build
    hist_kernel<<<eGrid, b256, 0, stream>>>(eidx, ideg, E_);
    alloc_kernel<<<nGrid, b256, 0, stream>>>(ideg, istart, icursor, counter, n);
    scatter_kernel<<<eGrid, b256, 0, stream>>>(eidx, icursor, edata, E_);
    // aggregate into ag
    aggr_kernel<<<n4Grid, b256, 0, stream>>>(Vb, attnW, istart, ideg, edata, ag, n);
    // Wo + residual + fused LN2: x2 -> d_out (fp32), h2 (bf16, overlays r2)
    gemm_lds<false, false, true, 1><<<dim3(rb, 1), b256, 0, stream>>>(
        ag, 128, Wt + 49152, 128, bo, out, 128, 0, x, 128, n, g2, be2, h2);
    // FFN1: h2 @ W1 + b1, ReLU -> u [N,512] bf16 (overlays h1|Q|K|V, all dead)
    gemm_lds<true, true, false, 1><<<dim3(rb, 4), b256, 0, stream>>>(
        h2, 128, Wt + 65536, 128, b1, uB, 512, 128, nullptr, 0, n, nullptr, nullptr, nullptr);
    // FFN2: u @ W2 + b2 + x2 -> d_out (K=512 -> 4 k-tiles)
    gemm_lds<false, false, false, 4><<<dim3(rb, 1), b256, 0, stream>>>(
        uB, 512, Wt + 131072, 512, b2, out, 128, 0, out, 128, n, nullptr, nullptr, nullptr);
}